// Round 1
// baseline (378.111 us; speedup 1.0000x reference)
//
#include <hip/hip_runtime.h>
#include <stdint.h>

#define DIM  1024
#define NSRC 4096
#define NTGT 4096

typedef __bf16 bf16_t;
typedef bf16_t bf16x8 __attribute__((ext_vector_type(8)));
typedef float  fx4    __attribute__((ext_vector_type(4)));

static __device__ __forceinline__ unsigned short f2bf(float f) {
  union { float f; uint32_t u; } v; v.f = f;
  return (unsigned short)((v.u + 0x7FFFu + ((v.u >> 16) & 1u)) >> 16);
}
static __device__ __forceinline__ float bf2f(unsigned short h) {
  union { uint32_t u; float f; } v; v.u = ((uint32_t)h) << 16;
  return v.f;
}

// async global->LDS, 16B per lane; lds dest is wave-uniform base + lane*16
static __device__ __forceinline__ void gl_lds16(const unsigned short* g, unsigned short* l) {
  __builtin_amdgcn_global_load_lds(
      (__attribute__((address_space(1))) const void*)g,
      (__attribute__((address_space(3))) void*)l, 16, 0, 0);
}

// ---------------- elementwise conversion ----------------
__global__ void k_f32_to_bf16(const float* __restrict__ in, unsigned short* __restrict__ out, int n4) {
  int i = blockIdx.x * blockDim.x + threadIdx.x;
  if (i >= n4) return;
  float4 v = ((const float4*)in)[i];
  ushort4 o;
  o.x = f2bf(v.x); o.y = f2bf(v.y); o.z = f2bf(v.z); o.w = f2bf(v.w);
  ((ushort4*)out)[i] = o;
}

// transpose fp32 [R][C] -> bf16 [C][R]
__global__ void k_transpose_bf16(const float* __restrict__ in, unsigned short* __restrict__ out,
                                 int R, int C) {
  __shared__ unsigned short tile[32][33];
  int c0 = blockIdx.x * 32, r0 = blockIdx.y * 32;
  int tx = threadIdx.x, ty = threadIdx.y; // 32 x 8
  for (int i = ty; i < 32; i += 8)
    tile[i][tx] = f2bf(in[(size_t)(r0 + i) * C + c0 + tx]);
  __syncthreads();
  for (int i = ty; i < 32; i += 8)
    out[(size_t)(c0 + i) * R + r0 + tx] = tile[tx][i];
}

// ---------------- row reductions ----------------
__global__ void k_rowsq(const unsigned short* __restrict__ x, float* __restrict__ sq, int cols) {
  int row = blockIdx.x;
  const unsigned short* p = x + (size_t)row * cols;
  int t = threadIdx.x;
  float s = 0.f;
  for (int i = t * 4; i < cols; i += blockDim.x * 4) {
    ushort4 v = *(const ushort4*)(p + i);
    float a = bf2f(v.x), b = bf2f(v.y), c = bf2f(v.z), d = bf2f(v.w);
    s += a * a + b * b + c * c + d * d;
  }
  for (int off = 32; off; off >>= 1) s += __shfl_down(s, off, 64);
  __shared__ float ws[4];
  int lane = t & 63, wv = t >> 6;
  if (lane == 0) ws[wv] = s;
  __syncthreads();
  if (t == 0) sq[row] = ws[0] + ws[1] + ws[2] + ws[3];
}

__global__ void k_rowsum_recip(const float* __restrict__ E, float* __restrict__ rinv, int cols) {
  int row = blockIdx.x;
  const float* p = E + (size_t)row * cols;
  int t = threadIdx.x;
  float s = 0.f;
  for (int i = t * 4; i < cols; i += blockDim.x * 4) {
    float4 v = *(const float4*)(p + i);
    s += v.x + v.y + v.z + v.w;
  }
  for (int off = 32; off; off >>= 1) s += __shfl_down(s, off, 64);
  __shared__ float ws[4];
  int lane = t & 63, wv = t >> 6;
  if (lane == 0) ws[wv] = s;
  __syncthreads();
  if (t == 0) rinv[row] = 1.0f / (ws[0] + ws[1] + ws[2] + ws[3]);
}

// K = E * rinv[row]; write fp32 in place + bf16 copy
__global__ void k_normalize(float* __restrict__ Kf, unsigned short* __restrict__ Kb,
                            const float* __restrict__ rinv, int cols4) {
  int i = blockIdx.x * blockDim.x + threadIdx.x; // float4 index
  int row = i / cols4;
  float r = rinv[row];
  float4 v = ((const float4*)Kf)[i];
  v.x *= r; v.y *= r; v.z *= r; v.w *= r;
  ((float4*)Kf)[i] = v;
  ushort4 o;
  o.x = f2bf(v.x); o.y = f2bf(v.y); o.z = f2bf(v.z); o.w = f2bf(v.w);
  ((ushort4*)Kb)[i] = o;
}

// ---------------- m97-style NT bf16 GEMM ----------------
// C[M][N] = A[M][K] * B[N][K]^T, 128x128 tile, BK=32, 256 threads (2x2 waves, 4x4 mfma tiles each)
// EPI 0: +bias[n], bf16 out.  EPI 1: exp(-sqrt(max(sqs+sqt-2c,0))*invT), f32 out.  EPI 2: f32 out.
template <int EPI>
__global__ void __launch_bounds__(256)
k_gemm_nt(const unsigned short* __restrict__ A, const unsigned short* __restrict__ B,
          int M, int N, int K,
          const float* __restrict__ bias, unsigned short* __restrict__ Cb,
          float* __restrict__ Cf,
          const float* __restrict__ sqs, const float* __restrict__ sqt,
          const float* __restrict__ tempPtr) {
  __shared__ unsigned short ldsA[128 * 32];
  __shared__ unsigned short ldsB[128 * 32];

  const int m0 = blockIdx.y * 128;
  const int n0 = blockIdx.x * 128;
  const int tid  = threadIdx.x;
  const int lane = tid & 63;
  const int wv   = tid >> 6;
  const int wm   = wv >> 1, wn = wv & 1;

  // staging: 8 chunks of 1KB per tile; wave wv handles chunks wv*2, wv*2+1
  const int c0    = wv * 2;
  const int srow  = lane >> 2;       // 0..15 within chunk
  const int skoff = (lane & 3) * 8;  // bf16 elements within BK=32
  const unsigned short* ag[2]; const unsigned short* bg[2];
  unsigned short* la[2]; unsigned short* lb[2];
#pragma unroll
  for (int j = 0; j < 2; ++j) {
    int c = c0 + j;
    ag[j] = A + (size_t)(m0 + c * 16 + srow) * K + skoff;
    bg[j] = B + (size_t)(n0 + c * 16 + srow) * K + skoff;
    la[j] = ldsA + c * 512;
    lb[j] = ldsB + c * 512;
  }

  const fx4 fzero = {0.f, 0.f, 0.f, 0.f};
  fx4 acc[4][4];
#pragma unroll
  for (int i = 0; i < 4; ++i)
#pragma unroll
    for (int j = 0; j < 4; ++j) acc[i][j] = fzero;

  const int frow = lane & 15;
  const int kq   = lane >> 4; // 0..3
  const int aoff = (wm * 64 + frow) * 32 + kq * 8;
  const int boff = (wn * 64 + frow) * 32 + kq * 8;

  for (int ko = 0; ko < K; ko += 32) {
    gl_lds16(ag[0] + ko, la[0]);
    gl_lds16(ag[1] + ko, la[1]);
    gl_lds16(bg[0] + ko, lb[0]);
    gl_lds16(bg[1] + ko, lb[1]);
    __syncthreads();
    bf16x8 af[4], bfr[4];
#pragma unroll
    for (int t = 0; t < 4; ++t) af[t]  = *(const bf16x8*)(ldsA + aoff + t * 512);
#pragma unroll
    for (int t = 0; t < 4; ++t) bfr[t] = *(const bf16x8*)(ldsB + boff + t * 512);
#pragma unroll
    for (int i = 0; i < 4; ++i)
#pragma unroll
      for (int j = 0; j < 4; ++j)
        acc[i][j] = __builtin_amdgcn_mfma_f32_16x16x32_bf16(af[i], bfr[j], acc[i][j], 0, 0, 0);
    __syncthreads();
  }

  // epilogue: C/D layout col=lane&15, row=(lane>>4)*4+r
  const int col0  = n0 + wn * 64 + (lane & 15);
  const int row00 = m0 + wm * 64 + (lane >> 4) * 4;

  if constexpr (EPI == 0) {
#pragma unroll
    for (int j = 0; j < 4; ++j) {
      int gn = col0 + j * 16;
      float bj = bias[gn];
#pragma unroll
      for (int i = 0; i < 4; ++i)
#pragma unroll
        for (int r = 0; r < 4; ++r) {
          int gm = row00 + i * 16 + r;
          Cb[(size_t)gm * N + gn] = f2bf(acc[i][j][r] + bj);
        }
    }
  } else if constexpr (EPI == 1) {
    const float invT = 1.0f / tempPtr[0];
#pragma unroll
    for (int i = 0; i < 4; ++i)
#pragma unroll
      for (int r = 0; r < 4; ++r) {
        int gm = row00 + i * 16 + r;
        float si = sqs[gm];
#pragma unroll
        for (int j = 0; j < 4; ++j) {
          int gn = col0 + j * 16;
          float d2 = si + sqt[gn] - 2.0f * acc[i][j][r];
          float c = sqrtf(fmaxf(d2, 0.0f));
          Cf[(size_t)gm * N + gn] = __expf(-c * invT);
        }
      }
  } else {
#pragma unroll
    for (int i = 0; i < 4; ++i)
#pragma unroll
      for (int j = 0; j < 4; ++j)
#pragma unroll
        for (int r = 0; r < 4; ++r) {
          int gm = row00 + i * 16 + r;
          int gn = col0 + j * 16;
          Cf[(size_t)gm * N + gn] = acc[i][j][r];
        }
  }
}

// ---------------- launch ----------------
extern "C" void kernel_launch(void* const* d_in, const int* in_sizes, int n_in,
                              void* d_out, int out_size, void* d_ws, size_t ws_size,
                              hipStream_t stream) {
  const float* source = (const float*)d_in[0];
  const float* target = (const float*)d_in[1];
  const float* W_src  = (const float*)d_in[2];
  const float* b_src  = (const float*)d_in[3];
  const float* W_tgt  = (const float*)d_in[4];
  const float* b_tgt  = (const float*)d_in[5];
  const float* temp   = (const float*)d_in[6];

  float* out     = (float*)d_out;
  float* aligned = out;                         // [NSRC][DIM]
  float* Kout    = out + (size_t)NSRC * DIM;    // [NSRC][NTGT] (E, then normalized in place)

  char* ws = (char*)d_ws;
  unsigned short* src_b  = (unsigned short*)(ws + 0);
  unsigned short* tgt_b  = (unsigned short*)(ws + 8388608);
  unsigned short* Wsrc_b = (unsigned short*)(ws + 16777216);
  unsigned short* Wtgt_b = (unsigned short*)(ws + 18874368);
  unsigned short* sp_b   = (unsigned short*)(ws + 20971520);
  unsigned short* tp_b   = (unsigned short*)(ws + 29360128);
  unsigned short* tgtT_b = (unsigned short*)(ws + 37748736);
  unsigned short* K_b    = (unsigned short*)(ws + 46137344);
  float* sq_s = (float*)(ws + 79691776);
  float* sq_t = (float*)(ws + 79708160);
  float* rinv = (float*)(ws + 79724544);

  // 1) fp32 -> bf16 conversions
  k_f32_to_bf16<<<NSRC * DIM / 4 / 256, 256, 0, stream>>>(source, src_b, NSRC * DIM / 4);
  k_f32_to_bf16<<<NTGT * DIM / 4 / 256, 256, 0, stream>>>(target, tgt_b, NTGT * DIM / 4);
  k_f32_to_bf16<<<DIM * DIM / 4 / 256, 256, 0, stream>>>(W_src, Wsrc_b, DIM * DIM / 4);
  k_f32_to_bf16<<<DIM * DIM / 4 / 256, 256, 0, stream>>>(W_tgt, Wtgt_b, DIM * DIM / 4);
  k_transpose_bf16<<<dim3(DIM / 32, NTGT / 32), dim3(32, 8), 0, stream>>>(target, tgtT_b, NTGT, DIM);

  // 2) projections: sp = src @ Wsrc^T + b_src (bf16 out)
  k_gemm_nt<0><<<dim3(DIM / 128, NSRC / 128), 256, 0, stream>>>(
      src_b, Wsrc_b, NSRC, DIM, DIM, b_src, sp_b, nullptr, nullptr, nullptr, nullptr);
  k_gemm_nt<0><<<dim3(DIM / 128, NTGT / 128), 256, 0, stream>>>(
      tgt_b, Wtgt_b, NTGT, DIM, DIM, b_tgt, tp_b, nullptr, nullptr, nullptr, nullptr);

  // 3) row squared norms
  k_rowsq<<<NSRC, 256, 0, stream>>>(sp_b, sq_s, DIM);
  k_rowsq<<<NTGT, 256, 0, stream>>>(tp_b, sq_t, DIM);

  // 4) E = exp(-cost/T) into d_out K region
  k_gemm_nt<1><<<dim3(NTGT / 128, NSRC / 128), 256, 0, stream>>>(
      sp_b, tp_b, NSRC, NTGT, DIM, nullptr, nullptr, Kout, sq_s, sq_t, temp);

  // 5) row-normalize -> K (fp32 in d_out) + bf16 copy for the last GEMM
  k_rowsum_recip<<<NSRC, 256, 0, stream>>>(Kout, rinv, NTGT);
  k_normalize<<<NSRC * NTGT / 4 / 256, 256, 0, stream>>>(Kout, K_b, rinv, NTGT / 4);

  // 6) aligned = K @ target   (B = target^T bf16, NT layout)
  k_gemm_nt<2><<<dim3(DIM / 128, NSRC / 128), 256, 0, stream>>>(
      K_b, tgtT_b, NSRC, DIM, NTGT, nullptr, nullptr, aligned, nullptr, nullptr, nullptr);
}

// Round 2
// 347.146 us; speedup vs baseline: 1.0892x; 1.0892x over previous
//
#include <hip/hip_runtime.h>
#include <stdint.h>

#define DIM  1024
#define NSRC 4096
#define NTGT 4096

typedef __bf16 bf16_t;
typedef bf16_t bf16x8 __attribute__((ext_vector_type(8)));
typedef float  fx4    __attribute__((ext_vector_type(4)));

static __device__ __forceinline__ unsigned short f2bf(float f) {
  union { float f; uint32_t u; } v; v.f = f;
  return (unsigned short)((v.u + 0x7FFFu + ((v.u >> 16) & 1u)) >> 16);
}
static __device__ __forceinline__ float bf2f(unsigned short h) {
  union { uint32_t u; float f; } v; v.u = ((uint32_t)h) << 16;
  return v.f;
}

// async global->LDS, 16B per lane; lds dest is wave-uniform base + lane*16
static __device__ __forceinline__ void gl_lds16(const unsigned short* g, unsigned short* l) {
  __builtin_amdgcn_global_load_lds(
      (__attribute__((address_space(1))) const void*)g,
      (__attribute__((address_space(3))) void*)l, 16, 0, 0);
}

// ---------------- fused fp32->bf16 conversion of all four inputs ----------------
// blocks: [0,4096) source, [4096,8192) target, [8192,9216) W_src, [9216,10240) W_tgt
__global__ void k_convert_all(const float* __restrict__ s, const float* __restrict__ t,
                              const float* __restrict__ w0, const float* __restrict__ w1,
                              unsigned short* __restrict__ sb, unsigned short* __restrict__ tb,
                              unsigned short* __restrict__ wb0, unsigned short* __restrict__ wb1) {
  int b = blockIdx.x;
  const float* in; unsigned short* out; int idx;
  if (b < 4096)      { in = s;  out = sb;  idx = b * 256 + threadIdx.x; }
  else if (b < 8192) { in = t;  out = tb;  idx = (b - 4096) * 256 + threadIdx.x; }
  else if (b < 9216) { in = w0; out = wb0; idx = (b - 8192) * 256 + threadIdx.x; }
  else               { in = w1; out = wb1; idx = (b - 9216) * 256 + threadIdx.x; }
  float4 v = ((const float4*)in)[idx];
  ushort4 o;
  o.x = f2bf(v.x); o.y = f2bf(v.y); o.z = f2bf(v.z); o.w = f2bf(v.w);
  ((ushort4*)out)[idx] = o;
}

// transpose fp32 [R][C] -> bf16 [C][R]
__global__ void k_transpose_bf16(const float* __restrict__ in, unsigned short* __restrict__ out,
                                 int R, int C) {
  __shared__ unsigned short tile[32][33];
  int c0 = blockIdx.x * 32, r0 = blockIdx.y * 32;
  int tx = threadIdx.x, ty = threadIdx.y; // 32 x 8
  for (int i = ty; i < 32; i += 8)
    tile[i][tx] = f2bf(in[(size_t)(r0 + i) * C + c0 + tx]);
  __syncthreads();
  for (int i = ty; i < 32; i += 8)
    out[(size_t)(c0 + i) * R + r0 + tx] = tile[tx][i];
}

// ---------------- row squared norms for sp and tp in one launch ----------------
__global__ void k_rowsq2(const unsigned short* __restrict__ sp, const unsigned short* __restrict__ tp,
                         float* __restrict__ sqs, float* __restrict__ sqt, int cols) {
  int row = blockIdx.x;
  const unsigned short* p; float* o; int r;
  if (row < NSRC) { p = sp; o = sqs; r = row; }
  else            { p = tp; o = sqt; r = row - NSRC; }
  p += (size_t)r * cols;
  int t = threadIdx.x;
  float s = 0.f;
  for (int i = t * 4; i < cols; i += blockDim.x * 4) {
    ushort4 v = *(const ushort4*)(p + i);
    float a = bf2f(v.x), b = bf2f(v.y), c = bf2f(v.z), d = bf2f(v.w);
    s += a * a + b * b + c * c + d * d;
  }
  for (int off = 32; off; off >>= 1) s += __shfl_down(s, off, 64);
  __shared__ float ws[4];
  if ((t & 63) == 0) ws[t >> 6] = s;
  __syncthreads();
  if (t == 0) o[r] = ws[0] + ws[1] + ws[2] + ws[3];
}

// ---------------- row-normalize K in place (register-resident), emit rinv ----------------
// one block per row of 4096 fp32: 256 thr x 4 float4
__global__ void k_rownorm(float* __restrict__ Kf, float* __restrict__ rinv) {
  int row = blockIdx.x;
  float* p = Kf + (size_t)row * NTGT;
  int t = threadIdx.x;
  float4 v[4];
  float s = 0.f;
#pragma unroll
  for (int c = 0; c < 4; ++c) {
    v[c] = ((const float4*)p)[t + c * 256];
    s += v[c].x + v[c].y + v[c].z + v[c].w;
  }
  for (int off = 32; off; off >>= 1) s += __shfl_down(s, off, 64);
  __shared__ float ws[4];
  if ((t & 63) == 0) ws[t >> 6] = s;
  __syncthreads();
  float r = 1.0f / (ws[0] + ws[1] + ws[2] + ws[3]);
  if (t == 0) rinv[row] = r;
#pragma unroll
  for (int c = 0; c < 4; ++c) {
    v[c].x *= r; v[c].y *= r; v[c].z *= r; v[c].w *= r;
    ((float4*)p)[t + c * 256] = v[c];
  }
}

// ---------------- m97-style NT bf16 GEMM, 128x128 tile, BK=32, 256 threads ----------------
// EPI 0: dual-problem proj (blockIdx.z selects set), +bias, bf16 out
// EPI 1: score: E=exp(-sqrt(max(sqs+sqt-2c,0))/T) -> fp32 Cf AND bf16 Cb0
// EPI 3: split-K (blockIdx.z = k-chunk), epilogue unsafeAtomicAdd(Cf, acc*rinv[row])
template <int EPI>
__global__ void __launch_bounds__(256)
k_gemm(const unsigned short* __restrict__ A0, const unsigned short* __restrict__ B0,
       const unsigned short* __restrict__ A1, const unsigned short* __restrict__ B1,
       int N, int K,
       const float* __restrict__ bias0, const float* __restrict__ bias1,
       unsigned short* __restrict__ Cb0, unsigned short* __restrict__ Cb1,
       float* __restrict__ Cf,
       const float* __restrict__ sqs, const float* __restrict__ sqt,
       const float* __restrict__ tempPtr, const float* __restrict__ rinv,
       int KS) {
  __shared__ unsigned short ldsA[128 * 32];
  __shared__ unsigned short ldsB[128 * 32];

  const unsigned short* A = A0;
  const unsigned short* B = B0;
  const float* bias = bias0;
  unsigned short* Cb = Cb0;
  int k0 = 0, k1 = K;
  if constexpr (EPI == 0) {
    if (blockIdx.z) { A = A1; B = B1; bias = bias1; Cb = Cb1; }
  }
  if constexpr (EPI == 3) { k0 = blockIdx.z * KS; k1 = k0 + KS; }

  const int m0 = blockIdx.y * 128;
  const int n0 = blockIdx.x * 128;
  const int tid  = threadIdx.x;
  const int lane = tid & 63;
  const int wv   = tid >> 6;
  const int wm   = wv >> 1, wn = wv & 1;

  // staging: 8 chunks of 1KB per tile; wave wv handles chunks wv*2, wv*2+1
  const int c0    = wv * 2;
  const int srow  = lane >> 2;       // 0..15 within chunk
  const int skoff = (lane & 3) * 8;  // bf16 elements within BK=32
  const unsigned short* ag[2]; const unsigned short* bg[2];
  unsigned short* la[2]; unsigned short* lb[2];
#pragma unroll
  for (int j = 0; j < 2; ++j) {
    int c = c0 + j;
    ag[j] = A + (size_t)(m0 + c * 16 + srow) * K + skoff;
    bg[j] = B + (size_t)(n0 + c * 16 + srow) * K + skoff;
    la[j] = ldsA + c * 512;
    lb[j] = ldsB + c * 512;
  }

  const fx4 fzero = {0.f, 0.f, 0.f, 0.f};
  fx4 acc[4][4];
#pragma unroll
  for (int i = 0; i < 4; ++i)
#pragma unroll
    for (int j = 0; j < 4; ++j) acc[i][j] = fzero;

  const int frow = lane & 15;
  const int kq   = lane >> 4; // 0..3
  const int aoff = (wm * 64 + frow) * 32 + kq * 8;
  const int boff = (wn * 64 + frow) * 32 + kq * 8;

  for (int ko = k0; ko < k1; ko += 32) {
    gl_lds16(ag[0] + ko, la[0]);
    gl_lds16(ag[1] + ko, la[1]);
    gl_lds16(bg[0] + ko, lb[0]);
    gl_lds16(bg[1] + ko, lb[1]);
    __syncthreads();
    bf16x8 af[4], bfr[4];
#pragma unroll
    for (int t = 0; t < 4; ++t) af[t]  = *(const bf16x8*)(ldsA + aoff + t * 512);
#pragma unroll
    for (int t = 0; t < 4; ++t) bfr[t] = *(const bf16x8*)(ldsB + boff + t * 512);
#pragma unroll
    for (int i = 0; i < 4; ++i)
#pragma unroll
      for (int j = 0; j < 4; ++j)
        acc[i][j] = __builtin_amdgcn_mfma_f32_16x16x32_bf16(af[i], bfr[j], acc[i][j], 0, 0, 0);
    __syncthreads();
  }

  // epilogue: C/D layout col=lane&15, row=(lane>>4)*4+r
  const int col0  = n0 + wn * 64 + (lane & 15);
  const int row00 = m0 + wm * 64 + (lane >> 4) * 4;

  if constexpr (EPI == 0) {
#pragma unroll
    for (int j = 0; j < 4; ++j) {
      int gn = col0 + j * 16;
      float bj = bias[gn];
#pragma unroll
      for (int i = 0; i < 4; ++i)
#pragma unroll
        for (int r = 0; r < 4; ++r) {
          int gm = row00 + i * 16 + r;
          Cb[(size_t)gm * N + gn] = f2bf(acc[i][j][r] + bj);
        }
    }
  } else if constexpr (EPI == 1) {
    const float invT = 1.0f / tempPtr[0];
#pragma unroll
    for (int i = 0; i < 4; ++i)
#pragma unroll
      for (int r = 0; r < 4; ++r) {
        int gm = row00 + i * 16 + r;
        float si = sqs[gm];
#pragma unroll
        for (int j = 0; j < 4; ++j) {
          int gn = col0 + j * 16;
          float d2 = si + sqt[gn] - 2.0f * acc[i][j][r];
          float c = sqrtf(fmaxf(d2, 0.0f));
          float e = __expf(-c * invT);
          Cf[(size_t)gm * N + gn] = e;
          Cb[(size_t)gm * N + gn] = f2bf(e);
        }
      }
  } else { // EPI == 3
#pragma unroll
    for (int i = 0; i < 4; ++i)
#pragma unroll
      for (int r = 0; r < 4; ++r) {
        int gm = row00 + i * 16 + r;
        float rv = rinv[gm];
#pragma unroll
        for (int j = 0; j < 4; ++j) {
          int gn = col0 + j * 16;
          unsafeAtomicAdd(&Cf[(size_t)gm * N + gn], acc[i][j][r] * rv);
        }
      }
  }
}

// ---------------- launch ----------------
extern "C" void kernel_launch(void* const* d_in, const int* in_sizes, int n_in,
                              void* d_out, int out_size, void* d_ws, size_t ws_size,
                              hipStream_t stream) {
  const float* source = (const float*)d_in[0];
  const float* target = (const float*)d_in[1];
  const float* W_src  = (const float*)d_in[2];
  const float* b_src  = (const float*)d_in[3];
  const float* W_tgt  = (const float*)d_in[4];
  const float* b_tgt  = (const float*)d_in[5];
  const float* temp   = (const float*)d_in[6];

  float* out     = (float*)d_out;
  float* aligned = out;                         // [NSRC][DIM]
  float* Kout    = out + (size_t)NSRC * DIM;    // [NSRC][NTGT] (E, normalized in place)

  char* ws = (char*)d_ws;
  unsigned short* src_b  = (unsigned short*)(ws + 0);
  unsigned short* tgt_b  = (unsigned short*)(ws + 8388608);
  unsigned short* Wsrc_b = (unsigned short*)(ws + 16777216);
  unsigned short* Wtgt_b = (unsigned short*)(ws + 18874368);
  unsigned short* sp_b   = (unsigned short*)(ws + 20971520);
  unsigned short* tp_b   = (unsigned short*)(ws + 29360128);
  unsigned short* tgtT_b = (unsigned short*)(ws + 37748736);
  unsigned short* E_b    = (unsigned short*)(ws + 46137344); // 32 MB
  float* sq_s = (float*)(ws + 79691776);
  float* sq_t = (float*)(ws + 79708160);
  float* rinv = (float*)(ws + 79724544);

  // 0) zero the aligned accumulator region (d_out is poisoned before every launch)
  hipMemsetAsync(aligned, 0, (size_t)NSRC * DIM * sizeof(float), stream);

  // 1) conversions + target transpose
  k_convert_all<<<10240, 256, 0, stream>>>(source, target, W_src, W_tgt,
                                           src_b, tgt_b, Wsrc_b, Wtgt_b);
  k_transpose_bf16<<<dim3(DIM / 32, NTGT / 32), dim3(32, 8), 0, stream>>>(target, tgtT_b, NTGT, DIM);

  // 2) both projections in one dispatch (z selects problem)
  k_gemm<0><<<dim3(DIM / 128, NSRC / 128, 2), 256, 0, stream>>>(
      src_b, Wsrc_b, tgt_b, Wtgt_b, DIM, DIM, b_src, b_tgt, sp_b, tp_b,
      nullptr, nullptr, nullptr, nullptr, nullptr, 0);

  // 3) row squared norms (both in one dispatch)
  k_rowsq2<<<NSRC + NTGT, 256, 0, stream>>>(sp_b, tp_b, sq_s, sq_t, DIM);

  // 4) score: E fp32 -> d_out K region, E bf16 -> ws
  k_gemm<1><<<dim3(NTGT / 128, NSRC / 128, 1), 256, 0, stream>>>(
      sp_b, tp_b, nullptr, nullptr, NTGT, DIM, nullptr, nullptr, E_b, nullptr,
      Kout, sq_s, sq_t, temp, nullptr, 0);

  // 5) normalize K in place, emit rinv
  k_rownorm<<<NSRC, 256, 0, stream>>>(Kout, rinv);

  // 6) aligned = diag(rinv) * (E @ target): split-K x4, atomic accumulate
  k_gemm<3><<<dim3(DIM / 128, NSRC / 128, 4), 256, 0, stream>>>(
      E_b, tgtT_b, nullptr, nullptr, DIM, NTGT, nullptr, nullptr, nullptr, nullptr,
      aligned, nullptr, nullptr, nullptr, rinv, NTGT / 4);
}

// Round 3
// 334.543 us; speedup vs baseline: 1.1302x; 1.0377x over previous
//
#include <hip/hip_runtime.h>
#include <stdint.h>

#define DIM  1024
#define NSRC 4096
#define NTGT 4096

typedef __bf16 bf16_t;
typedef bf16_t bf16x8 __attribute__((ext_vector_type(8)));
typedef float  fx4    __attribute__((ext_vector_type(4)));

static __device__ __forceinline__ unsigned short f2bf(float f) {
  union { float f; uint32_t u; } v; v.f = f;
  return (unsigned short)((v.u + 0x7FFFu + ((v.u >> 16) & 1u)) >> 16);
}
static __device__ __forceinline__ float bf2f(unsigned short h) {
  union { uint32_t u; float f; } v; v.u = ((uint32_t)h) << 16;
  return v.f;
}

// async global->LDS, 16B per lane; lds dest is wave-uniform base + lane*16
static __device__ __forceinline__ void gl_lds16(const unsigned short* g, unsigned short* l) {
  __builtin_amdgcn_global_load_lds(
      (__attribute__((address_space(1))) const void*)g,
      (__attribute__((address_space(3))) void*)l, 16, 0, 0);
}

// ---------------- fused fp32->bf16 conversion of all four inputs ----------------
__global__ void k_convert_all(const float* __restrict__ s, const float* __restrict__ t,
                              const float* __restrict__ w0, const float* __restrict__ w1,
                              unsigned short* __restrict__ sb, unsigned short* __restrict__ tb,
                              unsigned short* __restrict__ wb0, unsigned short* __restrict__ wb1) {
  int b = blockIdx.x;
  const float* in; unsigned short* out; int idx;
  if (b < 4096)      { in = s;  out = sb;  idx = b * 256 + threadIdx.x; }
  else if (b < 8192) { in = t;  out = tb;  idx = (b - 4096) * 256 + threadIdx.x; }
  else if (b < 9216) { in = w0; out = wb0; idx = (b - 8192) * 256 + threadIdx.x; }
  else               { in = w1; out = wb1; idx = (b - 9216) * 256 + threadIdx.x; }
  float4 v = ((const float4*)in)[idx];
  ushort4 o;
  o.x = f2bf(v.x); o.y = f2bf(v.y); o.z = f2bf(v.z); o.w = f2bf(v.w);
  ((ushort4*)out)[idx] = o;
}

// transpose fp32 [R][C] -> bf16 [C][R]
__global__ void k_transpose_bf16(const float* __restrict__ in, unsigned short* __restrict__ out,
                                 int R, int C) {
  __shared__ unsigned short tile[32][33];
  int c0 = blockIdx.x * 32, r0 = blockIdx.y * 32;
  int tx = threadIdx.x, ty = threadIdx.y; // 32 x 8
  for (int i = ty; i < 32; i += 8)
    tile[i][tx] = f2bf(in[(size_t)(r0 + i) * C + c0 + tx]);
  __syncthreads();
  for (int i = ty; i < 32; i += 8)
    out[(size_t)(c0 + i) * R + r0 + tx] = tile[tx][i];
}

// ---------------- row squared norms for sp and tp in one launch ----------------
__global__ void k_rowsq2(const unsigned short* __restrict__ sp, const unsigned short* __restrict__ tp,
                         float* __restrict__ sqs, float* __restrict__ sqt, int cols) {
  int row = blockIdx.x;
  const unsigned short* p; float* o; int r;
  if (row < NSRC) { p = sp; o = sqs; r = row; }
  else            { p = tp; o = sqt; r = row - NSRC; }
  p += (size_t)r * cols;
  int t = threadIdx.x;
  float s = 0.f;
  for (int i = t * 4; i < cols; i += blockDim.x * 4) {
    ushort4 v = *(const ushort4*)(p + i);
    float a = bf2f(v.x), b = bf2f(v.y), c = bf2f(v.z), d = bf2f(v.w);
    s += a * a + b * b + c * c + d * d;
  }
  for (int off = 32; off; off >>= 1) s += __shfl_down(s, off, 64);
  __shared__ float ws[4];
  if ((t & 63) == 0) ws[t >> 6] = s;
  __syncthreads();
  if (t == 0) o[r] = ws[0] + ws[1] + ws[2] + ws[3];
}

// ---------------- rinv = 1/row_sums ----------------
__global__ void k_rinv(const float* __restrict__ rs, float* __restrict__ rinv) {
  int i = blockIdx.x * blockDim.x + threadIdx.x;
  rinv[i] = 1.0f / rs[i];
}

// ---------------- Kf = bf2f(E_b) * rinv[row] : 16B bf16 load, 32B f32 store ----------------
__global__ void k_kwrite(const unsigned short* __restrict__ Eb, float* __restrict__ Kf,
                         const float* __restrict__ rinv) {
  int i = blockIdx.x * blockDim.x + threadIdx.x; // ushort8 index, row = i >> 9
  float r = rinv[i >> 9];
  ushort4 a = ((const ushort4*)Eb)[2 * i];
  ushort4 b = ((const ushort4*)Eb)[2 * i + 1];
  float4 o0 = { bf2f(a.x) * r, bf2f(a.y) * r, bf2f(a.z) * r, bf2f(a.w) * r };
  float4 o1 = { bf2f(b.x) * r, bf2f(b.y) * r, bf2f(b.z) * r, bf2f(b.w) * r };
  ((float4*)Kf)[2 * i]     = o0;
  ((float4*)Kf)[2 * i + 1] = o1;
}

// ---------------- merge 4 split-K partials, scale by rinv ----------------
__global__ void k_merge(const float* __restrict__ P, float* __restrict__ out,
                        const float* __restrict__ rinv) {
  int i = blockIdx.x * blockDim.x + threadIdx.x; // float4 index, row = i >> 8
  float r = rinv[i >> 8];
  const size_t stride = (size_t)NSRC * DIM / 4;
  float4 a = ((const float4*)P)[i];
  float4 b = ((const float4*)P)[i + stride];
  float4 c = ((const float4*)P)[i + 2 * stride];
  float4 d = ((const float4*)P)[i + 3 * stride];
  float4 o = { (a.x + b.x + c.x + d.x) * r, (a.y + b.y + c.y + d.y) * r,
               (a.z + b.z + c.z + d.z) * r, (a.w + b.w + c.w + d.w) * r };
  ((float4*)out)[i] = o;
}

// ---------------- m97-style NT bf16 GEMM, 128x128 tile, BK=32, 256 threads ----------------
// EPI 0: dual-problem proj (blockIdx.z selects set), +bias, bf16 out
// EPI 1: score: E=exp(-sqrt(max(sqs+sqt-2c,0))/T) -> bf16 Cb0 + row-sum atomics into rsums
// EPI 3: split-K (blockIdx.z = k-chunk), plain partial store to Cf[z][M][N]
template <int EPI>
__global__ void __launch_bounds__(256)
k_gemm(const unsigned short* __restrict__ A0, const unsigned short* __restrict__ B0,
       const unsigned short* __restrict__ A1, const unsigned short* __restrict__ B1,
       int N, int K,
       const float* __restrict__ bias0, const float* __restrict__ bias1,
       unsigned short* __restrict__ Cb0, unsigned short* __restrict__ Cb1,
       float* __restrict__ Cf,
       const float* __restrict__ sqs, const float* __restrict__ sqt,
       const float* __restrict__ tempPtr, float* __restrict__ rsums,
       int KS) {
  __shared__ unsigned short ldsA[128 * 32];
  __shared__ unsigned short ldsB[128 * 32];

  const unsigned short* A = A0;
  const unsigned short* B = B0;
  const float* bias = bias0;
  unsigned short* Cb = Cb0;
  int k0 = 0, k1 = K;
  if constexpr (EPI == 0) {
    if (blockIdx.z) { A = A1; B = B1; bias = bias1; Cb = Cb1; }
  }
  if constexpr (EPI == 3) { k0 = blockIdx.z * KS; k1 = k0 + KS; }

  const int m0 = blockIdx.y * 128;
  const int n0 = blockIdx.x * 128;
  const int tid  = threadIdx.x;
  const int lane = tid & 63;
  const int wv   = tid >> 6;
  const int wm   = wv >> 1, wn = wv & 1;

  // staging: 8 chunks of 1KB per tile; wave wv handles chunks wv*2, wv*2+1
  const int c0    = wv * 2;
  const int srow  = lane >> 2;       // 0..15 within chunk
  const int skoff = (lane & 3) * 8;  // bf16 elements within BK=32
  const unsigned short* ag[2]; const unsigned short* bg[2];
  unsigned short* la[2]; unsigned short* lb[2];
#pragma unroll
  for (int j = 0; j < 2; ++j) {
    int c = c0 + j;
    ag[j] = A + (size_t)(m0 + c * 16 + srow) * K + skoff;
    bg[j] = B + (size_t)(n0 + c * 16 + srow) * K + skoff;
    la[j] = ldsA + c * 512;
    lb[j] = ldsB + c * 512;
  }

  const fx4 fzero = {0.f, 0.f, 0.f, 0.f};
  fx4 acc[4][4];
#pragma unroll
  for (int i = 0; i < 4; ++i)
#pragma unroll
    for (int j = 0; j < 4; ++j) acc[i][j] = fzero;

  const int frow = lane & 15;
  const int kq   = lane >> 4; // 0..3
  const int aoff = (wm * 64 + frow) * 32 + kq * 8;
  const int boff = (wn * 64 + frow) * 32 + kq * 8;

  for (int ko = k0; ko < k1; ko += 32) {
    gl_lds16(ag[0] + ko, la[0]);
    gl_lds16(ag[1] + ko, la[1]);
    gl_lds16(bg[0] + ko, lb[0]);
    gl_lds16(bg[1] + ko, lb[1]);
    __syncthreads();
    bf16x8 af[4], bfr[4];
#pragma unroll
    for (int t = 0; t < 4; ++t) af[t]  = *(const bf16x8*)(ldsA + aoff + t * 512);
#pragma unroll
    for (int t = 0; t < 4; ++t) bfr[t] = *(const bf16x8*)(ldsB + boff + t * 512);
#pragma unroll
    for (int i = 0; i < 4; ++i)
#pragma unroll
      for (int j = 0; j < 4; ++j)
        acc[i][j] = __builtin_amdgcn_mfma_f32_16x16x32_bf16(af[i], bfr[j], acc[i][j], 0, 0, 0);
    __syncthreads();
  }

  // epilogue: C/D layout col=lane&15, row=(lane>>4)*4+r
  const int col0  = n0 + wn * 64 + (lane & 15);
  const int row00 = m0 + wm * 64 + (lane >> 4) * 4;

  if constexpr (EPI == 0) {
#pragma unroll
    for (int j = 0; j < 4; ++j) {
      int gn = col0 + j * 16;
      float bj = bias[gn];
#pragma unroll
      for (int i = 0; i < 4; ++i)
#pragma unroll
        for (int r = 0; r < 4; ++r) {
          int gm = row00 + i * 16 + r;
          Cb[(size_t)gm * N + gn] = f2bf(acc[i][j][r] + bj);
        }
    }
  } else if constexpr (EPI == 1) {
    __shared__ float rsum[128];
    if (tid < 128) rsum[tid] = 0.f;
    __syncthreads();
    const float invT = 1.0f / tempPtr[0];
    const int lrow0 = wm * 64 + (lane >> 4) * 4;
#pragma unroll
    for (int i = 0; i < 4; ++i)
#pragma unroll
      for (int r = 0; r < 4; ++r) {
        int lrow = lrow0 + i * 16 + r;
        int gm = m0 + lrow;
        float si = sqs[gm];
        float rowacc = 0.f;
#pragma unroll
        for (int j = 0; j < 4; ++j) {
          int gn = col0 + j * 16;
          float d2 = si + sqt[gn] - 2.0f * acc[i][j][r];
          float c = sqrtf(fmaxf(d2, 0.0f));
          float e = __expf(-c * invT);
          Cb[(size_t)gm * N + gn] = f2bf(e);
          rowacc += e;
        }
        atomicAdd(&rsum[lrow], rowacc);
      }
    __syncthreads();
    if (tid < 128) atomicAdd(&rsums[m0 + tid], rsum[tid]);
  } else { // EPI == 3: partial store, layout Cf[z][M][N]
    float* Pz = Cf + (size_t)blockIdx.z * NSRC * DIM;
#pragma unroll
    for (int i = 0; i < 4; ++i)
#pragma unroll
      for (int j = 0; j < 4; ++j)
#pragma unroll
        for (int r = 0; r < 4; ++r) {
          int gm = row00 + i * 16 + r;
          int gn = col0 + j * 16;
          Pz[(size_t)gm * N + gn] = acc[i][j][r];
        }
  }
}

// ---------------- launch ----------------
extern "C" void kernel_launch(void* const* d_in, const int* in_sizes, int n_in,
                              void* d_out, int out_size, void* d_ws, size_t ws_size,
                              hipStream_t stream) {
  const float* source = (const float*)d_in[0];
  const float* target = (const float*)d_in[1];
  const float* W_src  = (const float*)d_in[2];
  const float* b_src  = (const float*)d_in[3];
  const float* W_tgt  = (const float*)d_in[4];
  const float* b_tgt  = (const float*)d_in[5];
  const float* temp   = (const float*)d_in[6];

  float* out     = (float*)d_out;
  float* aligned = out;                         // [NSRC][DIM]
  float* Kout    = out + (size_t)NSRC * DIM;    // [NSRC][NTGT] final K; staging for partials
  float* parts   = Kout;                        // 4 x [NSRC][DIM] fp32 = exactly 64 MB

  char* ws = (char*)d_ws;
  unsigned short* src_b  = (unsigned short*)(ws + 0);
  unsigned short* tgt_b  = (unsigned short*)(ws + 8388608);
  unsigned short* Wsrc_b = (unsigned short*)(ws + 16777216);
  unsigned short* Wtgt_b = (unsigned short*)(ws + 18874368);
  unsigned short* sp_b   = (unsigned short*)(ws + 20971520);
  unsigned short* tp_b   = (unsigned short*)(ws + 29360128);
  unsigned short* tgtT_b = (unsigned short*)(ws + 37748736);
  unsigned short* E_b    = (unsigned short*)(ws + 46137344); // 32 MB
  float* sq_s  = (float*)(ws + 79691776);
  float* sq_t  = (float*)(ws + 79708160);
  float* rsums = (float*)(ws + 79724544);
  float* rinv  = (float*)(ws + 79740928);

  // 0) zero the row-sum accumulator (ws is poisoned before every launch)
  hipMemsetAsync(rsums, 0, NSRC * sizeof(float), stream);

  // 1) conversions + target transpose
  k_convert_all<<<10240, 256, 0, stream>>>(source, target, W_src, W_tgt,
                                           src_b, tgt_b, Wsrc_b, Wtgt_b);
  k_transpose_bf16<<<dim3(DIM / 32, NTGT / 32), dim3(32, 8), 0, stream>>>(target, tgtT_b, NTGT, DIM);

  // 2) both projections in one dispatch (z selects problem)
  k_gemm<0><<<dim3(DIM / 128, NSRC / 128, 2), 256, 0, stream>>>(
      src_b, Wsrc_b, tgt_b, Wtgt_b, DIM, DIM, b_src, b_tgt, sp_b, tp_b,
      nullptr, nullptr, nullptr, nullptr, nullptr, 0);

  // 3) row squared norms (both in one dispatch)
  k_rowsq2<<<NSRC + NTGT, 256, 0, stream>>>(sp_b, tp_b, sq_s, sq_t, DIM);

  // 4) score: E bf16 -> ws, row sums -> rsums (global atomics)
  k_gemm<1><<<dim3(NTGT / 128, NSRC / 128, 1), 256, 0, stream>>>(
      sp_b, tp_b, nullptr, nullptr, NTGT, DIM, nullptr, nullptr, E_b, nullptr,
      nullptr, sq_s, sq_t, temp, rsums, 0);

  // 5) rinv
  k_rinv<<<NSRC / 256, 256, 0, stream>>>(rsums, rinv);

  // 6) E @ target: split-K x4, plain partial stores into d_out K region (dead until step 8)
  k_gemm<3><<<dim3(DIM / 128, NSRC / 128, 4), 256, 0, stream>>>(
      E_b, tgtT_b, nullptr, nullptr, DIM, NTGT, nullptr, nullptr, nullptr, nullptr,
      parts, nullptr, nullptr, nullptr, nullptr, NTGT / 4);

  // 7) merge partials * rinv -> aligned
  k_merge<<<NSRC * DIM / 4 / 256, 256, 0, stream>>>(parts, aligned, rinv);

  // 8) K = bf2f(E_b) * rinv -> d_out K region (overwrites partials)
  k_kwrite<<<NSRC * NTGT / 8 / 256, 256, 0, stream>>>(E_b, Kout, rinv);
}